// Round 2
// baseline (63276.471 us; speedup 1.0000x reference)
//
#include <hip/hip_runtime.h>
#include <hip/hip_fp16.h>
#include <stdint.h>

#define SEQ_LEN 16384
#define H       512
#define NWG     64      // workgroups; WG k owns h[8k..8k+8)
#define HK      8
#define T       256
#define NROWG   24      // gi rows per WG (3 gates x 8)
#define WPITCH  257     // uint32 pitch per weight row (256 data + 1 pad)

// exchange word: [f16 value (hi 16) | step tag (lo 16)]
__global__ void gru_init(uint32_t* __restrict__ tag32) {
    int i = blockIdx.x * blockDim.x + threadIdx.x;
    if (i < H) {
        __hip_atomic_store(&tag32[i],     0u,      __ATOMIC_RELAXED, __HIP_MEMORY_SCOPE_AGENT); // h0=0, tag 0
        __hip_atomic_store(&tag32[H + i], 0xFFFFu, __ATOMIC_RELAXED, __HIP_MEMORY_SCOPE_AGENT); // invalid tag
    }
}

__launch_bounds__(T, 1)
__global__ void gru_main(const float* __restrict__ x,
                         const float* __restrict__ Wih,
                         const float* __restrict__ Whh,
                         const float* __restrict__ bih,
                         const float* __restrict__ bhh,
                         float* __restrict__ out,
                         uint32_t* __restrict__ tag32)
{
    const int wg  = blockIdx.x;
    const int tid = threadIdx.x;
    const int j0  = wg * HK;

    __shared__ uint32_t w_lds[48 * WPITCH];   // rows 0..23 = W_ih, 24..47 = W_hh (f16 pairs)
    __shared__ float    x_lds[H];
    __shared__ float    h_lds[H];
    __shared__ float    pgi[8 * NROWG];       // gi partials [c][row]
    __shared__ float    phh[8 * NROWG];       // hh partials [c][row]
    __shared__ float    sums_g[NROWG];
    __shared__ float    sums_h[NROWG];
    __shared__ float    bsum_g[NROWG];
    __shared__ float    bsum_h[NROWG];

    __half* wh = (__half*)w_lds;              // half pitch = 2*WPITCH = 514

    // ---- prologue: stage weights f32 -> f16 LDS ----
    for (int idx = tid; idx < 48 * H; idx += T) {
        int r  = idx >> 9;                    // 0..47
        int k  = idx & (H - 1);
        int rr = (r < NROWG) ? r : r - NROWG;
        int g  = rr >> 3;
        int jj = rr & 7;
        int grow = g * H + j0 + jj;
        float w = (r < NROWG) ? Wih[(size_t)grow * H + k] : Whh[(size_t)grow * H + k];
        wh[r * (2 * WPITCH) + k] = __float2half(w);
    }
    if (tid < NROWG) {
        int g  = tid >> 3;
        int jj = tid & 7;
        int grow = g * H + j0 + jj;
        bsum_g[tid] = (g == 2) ? bih[grow] : (bih[grow] + bhh[grow]);
        bsum_h[tid] = (g == 2) ? bhh[grow] : 0.0f;
    }
    // prefill x_lds with x_0
    if (tid >= 64 && tid < 192) {
        int p = tid - 64;
        ((float4*)x_lds)[p] = ((const float4*)x)[p];
    }
    __syncthreads();

    const bool isPoll = (tid < 64);
    const int  l      = tid;                  // poll lane (wave 0)
    const int  ridx   = tid - 64;             // 0..191 for dotters
    const int  row24  = (ridx >= 0) ? (ridx % NROWG) : 0;
    const int  c8     = (ridx >= 0) ? (ridx / NROWG) : 0;   // 0..7

    float hprev = 0.0f;                       // f32 own h (lanes 0..7 of wave 0)
    float gsumR = 0.0f;

    for (int t = 0; t < SEQ_LEN; ++t) {
        float4 xpref;
        if (isPoll) {
            // ---- poll all 512 h elements: 8 coalesced 4B atomic loads in flight ----
            uint32_t need = (uint32_t)t & 0xFFFFu;
            uint32_t* base = tag32 + (size_t)(t & 1) * H;
            uint32_t vals[8];
            uint32_t pend = 0xFFu;
            while (pend) {
                uint32_t np = pend;
                #pragma unroll
                for (int q = 0; q < 8; ++q) {
                    if (pend & (1u << q)) {
                        uint32_t w = __hip_atomic_load(&base[l + 64 * q],
                                                       __ATOMIC_RELAXED, __HIP_MEMORY_SCOPE_AGENT);
                        if ((w & 0xFFFFu) == need) { vals[q] = w; np &= ~(1u << q); }
                    }
                }
                pend = np;
                if (pend) __builtin_amdgcn_s_sleep(1);
            }
            #pragma unroll
            for (int q = 0; q < 8; ++q)
                h_lds[l + 64 * q] =
                    __half2float(__ushort_as_half((unsigned short)(vals[q] >> 16)));
        } else {
            // issue x_{t+1} prefetch (latency hides under gi+hh dots)
            if (ridx < 128) {
                int tn = (t + 1 < SEQ_LEN) ? (t + 1) : 0;
                xpref = ((const float4*)(x + (size_t)tn * H))[ridx];
            }
            // ---- gi dots: row24 x chunk c8 over x_lds (no h dependency) ----
            const uint32_t* wrow = w_lds + row24 * WPITCH + c8 * 32;
            const float*    B    = x_lds + c8 * 64;
            float acc = 0.0f;
            #pragma unroll
            for (int i = 0; i < 32; ++i) {
                int s = (i + 4 * c8) & 31;                 // stagger: banks spread
                uint32_t wp = wrow[s];
                float2 wf = __half22float2(*(__half2*)&wp);
                acc = fmaf(wf.x, B[2 * s],     acc);
                acc = fmaf(wf.y, B[2 * s + 1], acc);
            }
            pgi[c8 * NROWG + row24] = acc;
        }
        __syncthreads();   // A: h_lds + pgi ready

        if (isPoll) {
            // reduce gi partials while dotters run hh
            if (l < NROWG) {
                float s = bsum_g[l];
                #pragma unroll
                for (int c = 0; c < 8; ++c) s += pgi[c * NROWG + l];
                gsumR = s;
            }
        } else {
            // ---- hh dots over h_lds ----
            const uint32_t* wrow = w_lds + (NROWG + row24) * WPITCH + c8 * 32;
            const float*    B    = h_lds + c8 * 64;
            float acc = 0.0f;
            #pragma unroll
            for (int i = 0; i < 32; ++i) {
                int s = (i + 4 * c8) & 31;
                uint32_t wp = wrow[s];
                float2 wf = __half22float2(*(__half2*)&wp);
                acc = fmaf(wf.x, B[2 * s],     acc);
                acc = fmaf(wf.y, B[2 * s + 1], acc);
            }
            phh[c8 * NROWG + row24] = acc;
            // commit x_{t+1} to LDS (gi dots for t are done)
            if (ridx < 128) ((float4*)x_lds)[ridx] = xpref;
        }
        __syncthreads();   // B: phh + x_lds(t+1) ready

        if (isPoll) {
            if (l < NROWG) {
                float s = bsum_h[l];
                #pragma unroll
                for (int c = 0; c < 8; ++c) s += phh[c * NROWG + l];
                sums_h[l] = s;
                sums_g[l] = gsumR;
            }
            // wave-internal LDS RAW: compiler inserts lgkmcnt wait; lanes 0..7 gates
            if (l < HK) {
                int jj = l;
                float ir = sums_g[jj], iz = sums_g[8 + jj], inn = sums_g[16 + jj];
                float hr = sums_h[jj], hz = sums_h[8 + jj], hn  = sums_h[16 + jj];
                float r_ = 1.0f / (1.0f + __expf(-(ir + hr)));
                float z_ = 1.0f / (1.0f + __expf(-(iz + hz)));
                float a  = inn + r_ * hn;
                a = fminf(12.0f, fmaxf(-12.0f, a));
                float e2 = __expf(2.0f * a);
                float n_ = (e2 - 1.0f) / (e2 + 1.0f);
                float hnew = (1.0f - z_) * n_ + z_ * hprev;
                out[(size_t)t * H + j0 + jj] = hnew;
                hprev = hnew;
                uint32_t pk = ((uint32_t)__half_as_ushort(__float2half(hnew)) << 16)
                            | ((uint32_t)(t + 1) & 0xFFFFu);
                __hip_atomic_store(&tag32[(size_t)((t + 1) & 1) * H + j0 + jj], pk,
                                   __ATOMIC_RELAXED, __HIP_MEMORY_SCOPE_AGENT);
            }
        }
        __syncthreads();   // C: sums consumed, x_lds/h_lds safe to rewrite
    }
}

extern "C" void kernel_launch(void* const* d_in, const int* in_sizes, int n_in,
                              void* d_out, int out_size, void* d_ws, size_t ws_size,
                              hipStream_t stream) {
    const float* x   = (const float*)d_in[0];
    const float* Wih = (const float*)d_in[1];
    const float* Whh = (const float*)d_in[2];
    const float* bih = (const float*)d_in[3];
    const float* bhh = (const float*)d_in[4];
    float* out = (float*)d_out;
    uint32_t* tag32 = (uint32_t*)d_ws;        // 2 * 512 * 4B = 4 KB

    gru_init<<<4, 256, 0, stream>>>(tag32);
    gru_main<<<NWG, T, 0, stream>>>(x, Wih, Whh, bih, bhh, out, tag32);
}

// Round 3
// 32360.587 us; speedup vs baseline: 1.9554x; 1.9554x over previous
//
#include <hip/hip_runtime.h>
#include <hip/hip_fp16.h>
#include <stdint.h>

#define SEQ_LEN 16384
#define H       512
#define NWG     32      // workgroups; WG k owns h[16k..16k+16)
#define HK      16
#define T       512
#define NR      48      // rows per matrix per WG (3 gates x 16)
#define WPITCH  257     // uint32 pitch per weight row (256 data + 1 pad)

// exchange word: [f16 value (hi 16) | step tag (lo 16)]
__global__ void gru_init(uint32_t* __restrict__ tag32) {
    int i = blockIdx.x * blockDim.x + threadIdx.x;
    if (i < H)
        __hip_atomic_store(&tag32[i], 0u, __ATOMIC_RELAXED, __HIP_MEMORY_SCOPE_AGENT);       // h0 = 0, tag 0
    else if (i < 2 * H)
        __hip_atomic_store(&tag32[i], 0xFFFFu, __ATOMIC_RELAXED, __HIP_MEMORY_SCOPE_AGENT);  // invalid tag
}

__launch_bounds__(T, 1)
__global__ void gru_main(const float* __restrict__ x,
                         const float* __restrict__ Wih,
                         const float* __restrict__ Whh,
                         const float* __restrict__ bih,
                         const float* __restrict__ bhh,
                         float* __restrict__ out,
                         uint32_t* __restrict__ tag32)
{
    const int wg  = blockIdx.x;
    const int tid = threadIdx.x;
    const int j0  = wg * HK;

    __shared__ uint32_t w_lds[2 * NR * WPITCH];  // rows 0..47 = W_ih slice, 48..95 = W_hh slice (f16 pairs)
    __shared__ float    x_lds[H];
    __shared__ float    h_lds[H];
    __shared__ float    pgi[4 * NR];             // gi partials [c4][row]
    __shared__ float    phh[8 * NR];             // hh partials [c8][row]
    __shared__ float    sums_g[NR];
    __shared__ float    bsum_g[NR];
    __shared__ float    bsum_h[NR];

    __half* wh = (__half*)w_lds;                 // half pitch = 2*WPITCH = 514

    // ---- prologue: stage weights f32 -> f16 LDS ----
    for (int idx = tid; idx < 2 * NR * H; idx += T) {
        int r  = idx >> 9;                       // 0..95
        int k  = idx & (H - 1);
        int rr = (r < NR) ? r : r - NR;          // 0..47
        int g  = rr >> 4;                        // gate
        int jj = rr & 15;
        int grow = g * H + j0 + jj;
        float w = (r < NR) ? Wih[(size_t)grow * H + k] : Whh[(size_t)grow * H + k];
        wh[r * (2 * WPITCH) + k] = __float2half(w);
    }
    if (tid < NR) {
        int g  = tid >> 4;
        int jj = tid & 15;
        int grow = g * H + j0 + jj;
        bsum_g[tid] = (g == 2) ? bih[grow] : (bih[grow] + bhh[grow]);
        bsum_h[tid] = (g == 2) ? bhh[grow] : 0.0f;
    }
    if (tid >= 448) {                            // prefill x_0
        int p = (tid - 448) * 2;
        ((float4*)x_lds)[p]     = ((const float4*)x)[p];
        ((float4*)x_lds)[p + 1] = ((const float4*)x)[p + 1];
    }
    __syncthreads();

    const bool isPoll = (tid < 256);
    const int  gp     = tid - 256;               // 0..255 for non-pollers
    const int  gi_row = (gp >= 0 && gp < 192) ? (gp % NR) : 0;
    const int  gi_c4  = (gp >= 0 && gp < 192) ? (gp / NR) : 0;
    const int  hh_row = tid % NR;                // for tid < 384 in hh phase
    const int  hh_c8  = tid / NR;

    float hprev = 0.0f;                          // exact f32 own h (tid 0..15)

    for (int t = 0; t < SEQ_LEN; ++t) {
        float4 xa, xb;
        if (isPoll) {
            // ---- tight dependent spin, 2 words per thread (round-1 style) ----
            uint32_t need = (uint32_t)t & 0xFFFFu;
            uint32_t* base = tag32 + (size_t)(t & 1) * H;
            int e0 = 2 * tid, e1 = e0 + 1;
            uint32_t v;
            do { v = __hip_atomic_load(&base[e0], __ATOMIC_RELAXED, __HIP_MEMORY_SCOPE_AGENT); }
            while ((v & 0xFFFFu) != need);
            h_lds[e0] = __half2float(__ushort_as_half((unsigned short)(v >> 16)));
            do { v = __hip_atomic_load(&base[e1], __ATOMIC_RELAXED, __HIP_MEMORY_SCOPE_AGENT); }
            while ((v & 0xFFFFu) != need);
            h_lds[e1] = __half2float(__ushort_as_half((unsigned short)(v >> 16)));
        } else {
            if (gp >= 192) {                     // issue x_{t+1} prefetch
                int tn = (t + 1 < SEQ_LEN) ? (t + 1) : 0;
                int p  = (gp - 192) * 2;
                xa = ((const float4*)(x + (size_t)tn * H))[p];
                xb = ((const float4*)(x + (size_t)tn * H))[p + 1];
            } else {
                // ---- gi dots: 48 rows x 4 chunks(128 cols) over x_lds ----
                const uint32_t* wrow = w_lds + gi_row * WPITCH + gi_c4 * 64;
                const float*    B    = x_lds + gi_c4 * 128;
                float acc = 0.0f;
                #pragma unroll
                for (int i = 0; i < 64; ++i) {
                    int s = (i + 8 * gi_c4) & 63;
                    uint32_t wp = wrow[s];
                    float2 wf = __half22float2(*(__half2*)&wp);
                    acc = fmaf(wf.x, B[2 * s],     acc);
                    acc = fmaf(wf.y, B[2 * s + 1], acc);
                }
                pgi[gi_c4 * NR + gi_row] = acc;
            }
        }
        __syncthreads();   // A: h_lds + pgi ready

        if (tid < 384) {
            // ---- hh dots: 48 rows x 8 chunks(64 cols) over h_lds ----
            const uint32_t* wrow = w_lds + (NR + hh_row) * WPITCH + hh_c8 * 32;
            const float*    B    = h_lds + hh_c8 * 64;
            float acc = 0.0f;
            #pragma unroll
            for (int i = 0; i < 32; ++i) {
                int s = (i + 4 * hh_c8) & 31;
                uint32_t wp = wrow[s];
                float2 wf = __half22float2(*(__half2*)&wp);
                acc = fmaf(wf.x, B[2 * s],     acc);
                acc = fmaf(wf.y, B[2 * s + 1], acc);
            }
            phh[hh_c8 * NR + hh_row] = acc;
        } else if (tid < 384 + NR) {
            // reduce gi partials (pgi ready since barrier A)
            int j = tid - 384;
            sums_g[j] = bsum_g[j] + pgi[j] + pgi[NR + j] + pgi[2 * NR + j] + pgi[3 * NR + j];
        } else if (tid >= 448) {
            // commit x_{t+1} (gi dots for step t already consumed x_lds)
            int p = (tid - 448) * 2;
            ((float4*)x_lds)[p]     = xa;
            ((float4*)x_lds)[p + 1] = xb;
        }
        __syncthreads();   // B: phh + sums_g + x_lds(t+1) ready

        if (tid < HK) {
            // fused hh reduce + gates + publish (16 threads)
            float sh0 = bsum_h[tid], sh1 = bsum_h[16 + tid], sh2 = bsum_h[32 + tid];
            #pragma unroll
            for (int c = 0; c < 8; ++c) {
                sh0 += phh[c * NR + tid];
                sh1 += phh[c * NR + 16 + tid];
                sh2 += phh[c * NR + 32 + tid];
            }
            float sg0 = sums_g[tid], sg1 = sums_g[16 + tid], sg2 = sums_g[32 + tid];
            float r_ = 1.0f / (1.0f + __expf(-(sg0 + sh0)));
            float z_ = 1.0f / (1.0f + __expf(-(sg1 + sh1)));
            float a  = sg2 + r_ * sh2;
            a = fminf(12.0f, fmaxf(-12.0f, a));
            float e2 = __expf(2.0f * a);
            float n_ = (e2 - 1.0f) / (e2 + 1.0f);
            float hnew = (1.0f - z_) * n_ + z_ * hprev;
            out[(size_t)t * H + j0 + tid] = hnew;
            hprev = hnew;
            uint32_t pk = ((uint32_t)__half_as_ushort(__float2half(hnew)) << 16)
                        | ((uint32_t)(t + 1) & 0xFFFFu);
            __hip_atomic_store(&tag32[(size_t)((t + 1) & 1) * H + j0 + tid], pk,
                               __ATOMIC_RELAXED, __HIP_MEMORY_SCOPE_AGENT);
        }
        __syncthreads();   // C: sums/partials consumed; LDS safe to rewrite
    }
}

extern "C" void kernel_launch(void* const* d_in, const int* in_sizes, int n_in,
                              void* d_out, int out_size, void* d_ws, size_t ws_size,
                              hipStream_t stream) {
    const float* x   = (const float*)d_in[0];
    const float* Wih = (const float*)d_in[1];
    const float* Whh = (const float*)d_in[2];
    const float* bih = (const float*)d_in[3];
    const float* bhh = (const float*)d_in[4];
    float* out = (float*)d_out;
    uint32_t* tag32 = (uint32_t*)d_ws;           // 2 * 512 * 4B = 4 KB

    gru_init<<<2, 512, 0, stream>>>(tag32);
    gru_main<<<NWG, T, 0, stream>>>(x, Wih, Whh, bih, bhh, out, tag32);
}

// Round 4
// 30911.148 us; speedup vs baseline: 2.0470x; 1.0469x over previous
//
#include <hip/hip_runtime.h>
#include <hip/hip_fp16.h>
#include <stdint.h>

#define SEQ_LEN 16384
#define H       512
#define NWG     32      // WG k owns h[16k..16k+16)
#define HK      16
#define T       512
#define NR      48      // rows per matrix per WG (3 gates x 16)
#define WPITCH  257     // uint32 pitch per weight row (256 data + 1 pad)

#define LD_A(p)   __hip_atomic_load((p),      __ATOMIC_RELAXED, __HIP_MEMORY_SCOPE_AGENT)
#define ST_A(p,v) __hip_atomic_store((p),(v), __ATOMIC_RELAXED, __HIP_MEMORY_SCOPE_AGENT)

// exchange word: [f16 value (hi 16) | step tag (lo 16)]
__global__ void gru_init(uint32_t* __restrict__ tag32) {
    int i = blockIdx.x * blockDim.x + threadIdx.x;
    if (i < H)            ST_A(&tag32[i], 0u);        // h0 = 0, tag 0
    else if (i < 2 * H)   ST_A(&tag32[i], 0xFFFFu);   // invalid tag
}

__launch_bounds__(T, 1)
__global__ void gru_main(const float* __restrict__ x,
                         const float* __restrict__ Wih,
                         const float* __restrict__ Whh,
                         const float* __restrict__ bih,
                         const float* __restrict__ bhh,
                         float* __restrict__ out,
                         uint32_t* __restrict__ tag32)
{
    const int wg  = blockIdx.x;
    const int tid = threadIdx.x;
    const int j0  = wg * HK;

    __shared__ uint32_t w_lds[2 * NR * WPITCH];  // rows 0..47 W_ih, 48..95 W_hh (f16 pairs)
    __shared__ float    x_lds[H];
    __shared__ float    h_lds[H];
    __shared__ float    sums_g[NR];
    __shared__ float    sums_h[NR];
    __shared__ float    bsum_g[NR];
    __shared__ float    bsum_h[NR];

    __half* wh = (__half*)w_lds;                 // half pitch = 2*WPITCH

    // ---- prologue: stage weights f32 -> f16 LDS ----
    for (int idx = tid; idx < 2 * NR * H; idx += T) {
        int r  = idx >> 9;                       // 0..95
        int k  = idx & (H - 1);
        int rr = (r < NR) ? r : r - NR;          // 0..47
        int g  = rr >> 4;
        int jj = rr & 15;
        int grow = g * H + j0 + jj;
        float w = (r < NR) ? Wih[(size_t)grow * H + k] : Whh[(size_t)grow * H + k];
        wh[r * (2 * WPITCH) + k] = __float2half(w);
    }
    if (tid < NR) {
        int g  = tid >> 4;
        int jj = tid & 15;
        int grow = g * H + j0 + jj;
        bsum_g[tid] = (g == 2) ? bih[grow] : (bih[grow] + bhh[grow]);
        bsum_h[tid] = (g == 2) ? bhh[grow] : 0.0f;
    }
    if (tid < 128)                               // prefill x_0
        ((float4*)x_lds)[tid] = ((const float4*)x)[tid];
    __syncthreads();

    const int wv = tid >> 6;                     // wave 0..7
    const int l  = tid & 63;
    const int c8 = l & 7;                        // chunk lane
    const int r8 = l >> 3;                       // row-in-wave

    float hprev = 0.0f;                          // exact f32 own h (tid 0..15)

    for (int t = 0; t < SEQ_LEN; ++t) {
        float4 xp;
        if (tid < 128) {
            // ---- issue x_{t+1} prefetch, then tight spin on 4 words (2x u64) ----
            int tn = (t + 1 < SEQ_LEN) ? (t + 1) : 0;
            xp = ((const float4*)(x + (size_t)tn * H))[tid];

            const uint32_t need = (uint32_t)t & 0xFFFFu;
            const unsigned long long want = (unsigned long long)need * 0x0000000100000001ull;
            const unsigned long long M    = 0x0000FFFF0000FFFFull;
            unsigned long long* base =
                (unsigned long long*)(tag32 + (size_t)(t & 1) * H) + 2 * tid;
            unsigned long long va, vb;
            for (;;) {
                va = LD_A(base);
                vb = LD_A(base + 1);
                if (((va & M) == want) & ((vb & M) == want)) break;
            }
            int e = 4 * tid;
            h_lds[e]     = __half2float(__ushort_as_half((unsigned short)(va >> 16)));
            h_lds[e + 1] = __half2float(__ushort_as_half((unsigned short)(va >> 48)));
            h_lds[e + 2] = __half2float(__ushort_as_half((unsigned short)(vb >> 16)));
            h_lds[e + 3] = __half2float(__ushort_as_half((unsigned short)(vb >> 48)));
        } else {
            // ---- gi dots (waves 2..7): row = 8*(wv-2)+r8, chunk c8 over x_lds ----
            int row = 8 * (wv - 2) + r8;
            const uint32_t* wrow = w_lds + row * WPITCH + c8 * 32;
            const float2*   B    = (const float2*)(x_lds + c8 * 64);
            float acc = 0.0f;
            #pragma unroll
            for (int i = 0; i < 32; ++i) {
                int s = (i + 4 * c8) & 31;
                uint32_t wp = wrow[s];
                float2 wf = __half22float2(*(__half2*)&wp);
                float2 b  = B[s];
                acc = fmaf(wf.x, b.x, fmaf(wf.y, b.y, acc));
            }
            acc += __shfl_xor(acc, 1);
            acc += __shfl_xor(acc, 2);
            acc += __shfl_xor(acc, 4);
            if (c8 == 0) sums_g[row] = acc + bsum_g[row];
        }
        __syncthreads();   // A: h_lds + sums_g ready

        if (tid < 384) {
            if (tid < 128) ((float4*)x_lds)[tid] = xp;   // commit x_{t+1}
            // ---- hh dots (waves 0..5): row = 8*wv+r8, chunk c8 over h_lds ----
            int row = 8 * wv + r8;
            const uint32_t* wrow = w_lds + (NR + row) * WPITCH + c8 * 32;
            const float2*   B    = (const float2*)(h_lds + c8 * 64);
            float acc = 0.0f;
            #pragma unroll
            for (int i = 0; i < 32; ++i) {
                int s = (i + 4 * c8) & 31;
                uint32_t wp = wrow[s];
                float2 wf = __half22float2(*(__half2*)&wp);
                float2 b  = B[s];
                acc = fmaf(wf.x, b.x, fmaf(wf.y, b.y, acc));
            }
            acc += __shfl_xor(acc, 1);
            acc += __shfl_xor(acc, 2);
            acc += __shfl_xor(acc, 4);
            if (c8 == 0) sums_h[row] = acc + bsum_h[row];
        }
        __syncthreads();   // B: sums_h + x_lds(t+1) ready

        if (tid < HK) {
            float sg0 = sums_g[tid], sg1 = sums_g[16 + tid], sg2 = sums_g[32 + tid];
            float sh0 = sums_h[tid], sh1 = sums_h[16 + tid], sh2 = sums_h[32 + tid];
            float r_ = 1.0f / (1.0f + __expf(-(sg0 + sh0)));
            float z_ = 1.0f / (1.0f + __expf(-(sg1 + sh1)));
            float a  = sg2 + r_ * sh2;
            a = fminf(12.0f, fmaxf(-12.0f, a));
            float e2 = __expf(2.0f * a);
            float n_ = (e2 - 1.0f) / (e2 + 1.0f);
            float hnew = (1.0f - z_) * n_ + z_ * hprev;
            out[(size_t)t * H + j0 + tid] = hnew;
            hprev = hnew;
            uint32_t pk = ((uint32_t)__half_as_ushort(__float2half(hnew)) << 16)
                        | ((uint32_t)(t + 1) & 0xFFFFu);
            ST_A(&tag32[(size_t)((t + 1) & 1) * H + j0 + tid], pk);
        }
        __syncthreads();   // C: sums consumed; LDS safe to rewrite
    }
}

extern "C" void kernel_launch(void* const* d_in, const int* in_sizes, int n_in,
                              void* d_out, int out_size, void* d_ws, size_t ws_size,
                              hipStream_t stream) {
    const float* x   = (const float*)d_in[0];
    const float* Wih = (const float*)d_in[1];
    const float* Whh = (const float*)d_in[2];
    const float* bih = (const float*)d_in[3];
    const float* bhh = (const float*)d_in[4];
    float* out = (float*)d_out;
    uint32_t* tag32 = (uint32_t*)d_ws;           // 2 * 512 * 4B = 4 KB

    gru_init<<<2, 512, 0, stream>>>(tag32);
    gru_main<<<NWG, T, 0, stream>>>(x, Wih, Whh, bih, bhh, out, tag32);
}